// Round 10
// baseline (328.545 us; speedup 1.0000x reference)
//
#include <hip/hip_runtime.h>

// Hamilton product of quaternions, layout (..., 4) = (w, x, y, z) contiguous.
// Shapes: q1, q2: (32, 4096, 64, 4) fp32 -> 8,388,608 quaternions.
// Memory-bound streaming op (402.7 MB traffic, roofline ~64us @ 6.3 TB/s).
//
// R3 lesson: VGPR=24 meant the compiler serialized loads into dependent
// load->vmcnt(0)->compute->store phases (~32B/lane in flight) -> latency-
// bound at 3.3 TB/s effective. Fix: 4 quats/thread, ALL 8 dwordx4 loads
// issued into named registers before any use (128 B/lane in flight), exact
// grid, no loop-carried dependence. Nontemporal stores keep the write-once
// output from evicting the L3-resident inputs (inputs = exactly 256 MiB).
//
// R9 lesson: __builtin_nontemporal_store needs a clang-native vector type,
// not HIP_vector_type float4 -> use ext_vector_type(4) float throughout.

typedef float f4 __attribute__((ext_vector_type(4)));

__device__ __forceinline__ f4 hprod(f4 a, f4 b) {
    f4 o;
    o.x = a.x * b.x - a.y * b.y - a.z * b.z - a.w * b.w;  // w
    o.y = a.x * b.y + a.y * b.x + a.z * b.w - a.w * b.z;  // x
    o.z = a.x * b.z - a.y * b.w + a.z * b.x + a.w * b.y;  // y
    o.w = a.x * b.w + a.y * b.z - a.z * b.y + a.w * b.x;  // z
    return o;
}

__global__ __launch_bounds__(256) void hamilton_kernel(
    const f4* __restrict__ q1,
    const f4* __restrict__ q2,
    f4* __restrict__ out,
    int n_quat)
{
    const int nt  = gridDim.x * blockDim.x;           // total threads
    const int tid = blockIdx.x * blockDim.x + threadIdx.x;

    const int i0 = tid;
    const int i1 = tid + nt;
    const int i2 = tid + 2 * nt;
    const int i3 = tid + 3 * nt;

    if (i3 < n_quat) {
        // Fast path: issue all 8 loads up front (8 x global_load_dwordx4,
        // 128 B/lane in flight), then compute+store with staged vmcnt waits.
        f4 a0 = q1[i0];
        f4 a1 = q1[i1];
        f4 a2 = q1[i2];
        f4 a3 = q1[i3];
        f4 b0 = q2[i0];
        f4 b1 = q2[i1];
        f4 b2 = q2[i2];
        f4 b3 = q2[i3];

        __builtin_nontemporal_store(hprod(a0, b0), &out[i0]);
        __builtin_nontemporal_store(hprod(a1, b1), &out[i1]);
        __builtin_nontemporal_store(hprod(a2, b2), &out[i2]);
        __builtin_nontemporal_store(hprod(a3, b3), &out[i3]);
    } else {
        // Tail (not taken for the bench shape: 8,388,608 = 4*256*8192 exact).
        if (i0 < n_quat) __builtin_nontemporal_store(hprod(q1[i0], q2[i0]), &out[i0]);
        if (i1 < n_quat) __builtin_nontemporal_store(hprod(q1[i1], q2[i1]), &out[i1]);
        if (i2 < n_quat) __builtin_nontemporal_store(hprod(q1[i2], q2[i2]), &out[i2]);
    }
}

extern "C" void kernel_launch(void* const* d_in, const int* in_sizes, int n_in,
                              void* d_out, int out_size, void* d_ws, size_t ws_size,
                              hipStream_t stream)
{
    const f4* q1 = (const f4*)d_in[0];
    const f4* q2 = (const f4*)d_in[1];
    f4* out = (f4*)d_out;

    int n_quat = in_sizes[0] / 4;   // 33,554,432 / 4 = 8,388,608

    const int block = 256;
    const int qpt = 4;              // quats per thread
    int grid = (n_quat + block * qpt - 1) / (block * qpt);   // 8192 exact
    if (grid < 1) grid = 1;

    hamilton_kernel<<<grid, block, 0, stream>>>(q1, q2, out, n_quat);
}

// Round 11
// 306.460 us; speedup vs baseline: 1.0721x; 1.0721x over previous
//
#include <hip/hip_runtime.h>

// Hamilton product of quaternions, layout (..., 4) = (w, x, y, z) contiguous.
// Shapes: q1, q2: (32, 4096, 64, 4) fp32 -> 8,388,608 quaternions.
// Memory-bound streaming op (402.7 MB logical traffic).
//
// R3:  grid-stride, far-strided segments, plain stores  -> ~120 us, 3.2 TB/s
// R10: exact-grid, 32-MiB-strided segments, NT stores   -> ~131 us, 3.1 TB/s
//   -> ILP/latency theory refuted (occupancy 73%, TLP sufficient).
//      Both used scattered per-block footprints. NT stores cost ~8%.
// R11 theory: the 2x gap vs m13's 6.29 TB/s copy is ADDRESS LOCALITY:
//   block-local striding gives each block one contiguous 16-KiB span per
//   array (device-wide linear walk, m13-like) instead of 12 fronts spread
//   over 32 MiB. Keep 4 independent loads/thread; plain stores.

typedef float f4 __attribute__((ext_vector_type(4)));

__device__ __forceinline__ f4 hprod(f4 a, f4 b) {
    f4 o;
    o.x = a.x * b.x - a.y * b.y - a.z * b.z - a.w * b.w;  // w
    o.y = a.x * b.y + a.y * b.x + a.z * b.w - a.w * b.z;  // x
    o.z = a.x * b.z - a.y * b.w + a.z * b.x + a.w * b.y;  // y
    o.w = a.x * b.w + a.y * b.z - a.z * b.y + a.w * b.x;  // z
    return o;
}

__global__ __launch_bounds__(256) void hamilton_kernel(
    const f4* __restrict__ q1,
    const f4* __restrict__ q2,
    f4* __restrict__ out,
    int n_quat)
{
    // Block b owns the contiguous range [b*1024, b*1024 + 1024).
    // Threads stride by 256 within it: 4 KiB per wave-instruction,
    // 16 KiB contiguous per array per block.
    const int base = blockIdx.x * (256 * 4) + threadIdx.x;
    const int i0 = base;
    const int i1 = base + 256;
    const int i2 = base + 512;
    const int i3 = base + 768;

    if (i3 < n_quat) {
        // All 8 loads issued before any consumer (128 B/lane in flight).
        f4 a0 = q1[i0];
        f4 a1 = q1[i1];
        f4 a2 = q1[i2];
        f4 a3 = q1[i3];
        f4 b0 = q2[i0];
        f4 b1 = q2[i1];
        f4 b2 = q2[i2];
        f4 b3 = q2[i3];

        out[i0] = hprod(a0, b0);
        out[i1] = hprod(a1, b1);
        out[i2] = hprod(a2, b2);
        out[i3] = hprod(a3, b3);
    } else {
        // Tail (not taken for the bench shape: 8,388,608 = 8192 * 1024 exact).
        if (i0 < n_quat) out[i0] = hprod(q1[i0], q2[i0]);
        if (i1 < n_quat) out[i1] = hprod(q1[i1], q2[i1]);
        if (i2 < n_quat) out[i2] = hprod(q1[i2], q2[i2]);
    }
}

extern "C" void kernel_launch(void* const* d_in, const int* in_sizes, int n_in,
                              void* d_out, int out_size, void* d_ws, size_t ws_size,
                              hipStream_t stream)
{
    const f4* q1 = (const f4*)d_in[0];
    const f4* q2 = (const f4*)d_in[1];
    f4* out = (f4*)d_out;

    int n_quat = in_sizes[0] / 4;   // 33,554,432 / 4 = 8,388,608

    const int block = 256;
    const int qpt = 4;              // quats per thread
    int grid = (n_quat + block * qpt - 1) / (block * qpt);   // 8192 exact
    if (grid < 1) grid = 1;

    hamilton_kernel<<<grid, block, 0, stream>>>(q1, q2, out, n_quat);
}